// Round 4
// baseline (467.484 us; speedup 1.0000x reference)
//
#include <hip/hip_runtime.h>
#include <cstdint>

typedef unsigned long long u64;
typedef float f32x4 __attribute__((ext_vector_type(4)));

#define BATCH   32
#define H       1024
#define W       1024
#define WPR     16                 // 64-bit words per row (1024/64)
#define TR      64                 // interior rows per tile
#define HALO    8                  // = generations
#define BR      (TR + 2*HALO)      // 80 buffer rows
#define BRP     (BR + 2)           // +2 zero-pad rows -> 82
#define WP      (WPR + 2)          // +2 zero-pad word-cols -> 18
#define THREADS 512
#define NWAVES  (THREADS/64)       // 8
#define GENS    8
#define GRID    (BATCH * (H / TR)) // 512 blocks
#define NTOT    33554432ULL        // B*H*W

// Horizontal 3-cell adder for one row: o = low bit, t = carry bit of (W+C+E).
__device__ __forceinline__ void hrow(u64 L, u64 C, u64 R, u64& o, u64& t) {
    u64 wv = (C << 1) | (L >> 63);
    u64 ev = (C >> 1) | (R << 63);
    o = wv ^ C ^ ev;
    t = (wv & C) | (ev & (wv ^ C));
}

// Combine 3 row-sums (2-bit each) -> next-state word. mid = center row word.
__device__ __forceinline__ u64 life_next(u64 oA, u64 tA, u64 oB, u64 tB,
                                         u64 oC, u64 tC, u64 mid) {
    u64 oa = oA ^ oB ^ oC;
    u64 oc = (oA & oB) | (oC & (oA ^ oB));
    u64 ts = tA ^ tB ^ tC;
    u64 tc = (tA & tB) | (tC & (tA ^ tB));
    u64 b1 = oc ^ ts;
    u64 cc = oc & ts;
    u64 b2 = cc ^ tc;
    u64 b3 = cc & tc;
    u64 eq3 = oa & b1 & ~(b2 | b3);          // sum9 == 3
    u64 eq4 = (~oa) & (~b1) & b2 & (~b3);    // sum9 == 4
    return eq3 | (mid & eq4);
}

// Fused: BALLOT pack fp32->bits (lane l compares float g*64+l; __ballot IS
// the packed word -- no shfl chains), 8 Life generations in LDS (paired-row
// updates, shrinking validity window). Target rows are loaded+packed INSIDE
// the gens steps (1 row/wave/step = exactly TR rows over 8 steps), hiding the
// 134 MB target read under gens compute. Epilogue: ZERO global reads, state
// AND target reconstructed from bits, ALIGNED nontemporal float4 stores.
// Reductions: wave shfl -> LDS -> ONE u64 atomic per block; tiny finalize
// kernel (no device-scope fences in the hot kernel).
__global__ __launch_bounds__(THREADS)
void gol_fused(const float* __restrict__ in_state,
               const float* __restrict__ target,
               float* __restrict__ out,
               u64* __restrict__ counters)
{
    __shared__ u64 buf[2][BRP][WP];      // 2*82*18*8 = 23616 B
    __shared__ u64 tbits[TR][WPR + 1];   // 64*17*8   =  8704 B (+1 zero col)
    __shared__ unsigned int wsum[NWAVES];

    const int tile = blockIdx.x;             // 0..511
    const int tpb  = H / TR;                 // 16 tiles per batch
    const int b    = tile / tpb;
    const int r0   = (tile - b * tpb) * TR;  // first interior global row

    const int tid  = threadIdx.x;
    const int wave = tid >> 6;
    const int lane = tid & 63;

    // Zero both gen-buffers (pads + out-of-range rows must stay zero).
    for (int i = tid; i < 2 * BRP * WP; i += THREADS)
        ((u64*)buf)[i] = 0ULL;
    if (tid < TR) tbits[tid][WPR] = 0ULL;    // zero pad word for epilogue reads
    __syncthreads();

    const size_t boff = (size_t)b * H * W;
    const float* inb  = in_state + boff;
    const float* tgb  = target + boff;

    // ---- ballot pack in_state: buffer row br <- global row r0-HALO+br ----
    // Word g of a row = bits for floats [64g, 64g+63]; lane l supplies bit l.
    for (int br = wave; br < BR; br += NWAVES) {
        int gr = r0 - HALO + br;
        if (gr < 0 || gr >= H) continue;    // wave-uniform
        const float* rowp = inb + (size_t)gr * W;
        u64 myw = 0;
        #pragma unroll
        for (int g = 0; g < 16; ++g) {
            float f = rowp[g * 64 + lane];
            u64 m = __ballot(f > 0.5f);
            if (lane == g) myw = m;
        }
        if (lane < 16)
            buf[0][br + 1][lane + 1] = myw;
    }
    __syncthreads();

    // ---- 8 generations, bit-parallel full adders, paired rows ----
    // State s valid on buffer rows [s, 79-s]; step s computes state s+1 on
    // [s+1, 78-s] (width 78-2s even -> clean row pairs).
    // Each step ALSO packs one target row per wave (loads issued first, so
    // HBM latency hides under the step's gens VALU).
    int cur = 0;
    for (int step = 0; step < GENS; ++step) {
        // issue target loads for this step's row early
        const int lr = step * NWAVES + wave;          // 0..63
        const float* trowp = tgb + (size_t)(r0 + lr) * W;
        float tf[16];
        #pragma unroll
        for (int g = 0; g < 16; ++g)
            tf[g] = trowp[g * 64 + lane];

        const int lo     = step + 1;            // first output buffer-row
        const int npairs = 39 - step;           // (78-2*step)/2
        const int items  = npairs * WPR;
        for (int idx = tid; idx < items; idx += THREADS) {
            int pr  = idx >> 4;
            int c   = (idx & 15) + 1;
            int br0 = lo + 2 * pr;              // first output row of pair
            int r   = br0 + 1;                  // array row (pad offset)

            u64 o0, t0, o1, t1, o2, t2, o3, t3, mB, mC;
            { u64 L = buf[cur][r-1][c-1], C = buf[cur][r-1][c], R = buf[cur][r-1][c+1];
              hrow(L, C, R, o0, t0); }
            { u64 L = buf[cur][r  ][c-1], C = buf[cur][r  ][c], R = buf[cur][r  ][c+1];
              hrow(L, C, R, o1, t1); mB = C; }
            { u64 L = buf[cur][r+1][c-1], C = buf[cur][r+1][c], R = buf[cur][r+1][c+1];
              hrow(L, C, R, o2, t2); mC = C; }
            { u64 L = buf[cur][r+2][c-1], C = buf[cur][r+2][c], R = buf[cur][r+2][c+1];
              hrow(L, C, R, o3, t3); }

            u64 n0 = life_next(o0, t0, o1, t1, o2, t2, mB);
            u64 n1 = life_next(o1, t1, o2, t2, o3, t3, mC);

            int gr0 = r0 - HALO + br0;
            buf[cur ^ 1][r    ][c] = (gr0     >= 0 && gr0     < H) ? n0 : 0ULL;
            buf[cur ^ 1][r + 1][c] = (gr0 + 1 >= 0 && gr0 + 1 < H) ? n1 : 0ULL;
        }

        // consume target loads: ballot-pack this step's row into tbits
        {
            u64 myw = 0;
            #pragma unroll
            for (int g = 0; g < 16; ++g) {
                u64 m = __ballot(tf[g] > 0.5f);
                if (lane == g) myw = m;
            }
            if (lane < 16)
                tbits[lr][lane] = myw;
        }

        __syncthreads();
        cur ^= 1;
    }
    // After 8 flips cur == 0; state-8 valid on rows [HALO, HALO+TR-1].

    // ---- epilogue: ZERO global reads; shifted quads, all stores 16B-aligned.
    // out layout: out[0]=loss, out[1..]=state, out[1+NTOT..]=target copy.
    // Quad k (k=0..254) covers row elements 4k+3..4k+6; out index
    // rowbase + 1 + 4k+3 === 0 mod 4. One lane/row handles head(3)+tail(1).
    float* o_state = out + 1;
    float* o_tgt   = out + 1 + NTOT;

    unsigned int mism = 0, live = 0;
    for (int lr = wave; lr < TR; lr += NWAVES) {
        int br = HALO + lr;
        int gr = r0 + lr;
        size_t rowbase = boff + (size_t)gr * W;
        const u64* wrow = &buf[cur][br + 1][1];   // wrow[0..15] data, wrow[16]=0 pad
        const u64* trow = &tbits[lr][0];          // trow[0..15] data, trow[16]=0 pad
        float* osrow = o_state + rowbase;
        float* otrow = o_tgt + rowbase;
        #pragma unroll
        for (int g = 0; g < 4; ++g) {
            int k = g * 64 + lane;
            if (k < 255) {
                int bitbase = 4 * k + 3;
                int w0 = bitbase >> 6;
                int sh = bitbase & 63;            // in {3,7,...,63}, never 0
                u64 slo = wrow[w0], shi = wrow[w0 + 1];
                u64 tlo = trow[w0], thi = trow[w0 + 1];
                unsigned sb = (unsigned)(((slo >> sh) | (shi << (64 - sh))) & 0xFULL);
                unsigned tb = (unsigned)(((tlo >> sh) | (thi << (64 - sh))) & 0xFULL);
                mism += (unsigned)__popc(sb ^ tb);
                live += (unsigned)__popc(sb);
                f32x4 sv, tv;
                sv.x = (float)(sb & 1u);
                sv.y = (float)((sb >> 1) & 1u);
                sv.z = (float)((sb >> 2) & 1u);
                sv.w = (float)((sb >> 3) & 1u);
                tv.x = (float)(tb & 1u);
                tv.y = (float)((tb >> 1) & 1u);
                tv.z = (float)((tb >> 2) & 1u);
                tv.w = (float)((tb >> 3) & 1u);
                __builtin_nontemporal_store(sv, (f32x4*)(osrow + bitbase));  // aligned
                __builtin_nontemporal_store(tv, (f32x4*)(otrow + bitbase));  // aligned
            } else {
                // head elements 0,1,2 and tail element 1023
                u64 sfirst = wrow[0],  slast = wrow[15];
                u64 tfirst = trow[0],  tlast = trow[15];
                unsigned shb = (unsigned)(sfirst & 7ULL);
                unsigned thb = (unsigned)(tfirst & 7ULL);
                unsigned stb = (unsigned)(slast >> 63);
                unsigned ttb = (unsigned)(tlast >> 63);
                mism += (unsigned)__popc(shb ^ thb) + (stb ^ ttb);
                live += (unsigned)__popc(shb) + stb;
                osrow[0]    = (float)(shb & 1u);
                osrow[1]    = (float)((shb >> 1) & 1u);
                osrow[2]    = (float)((shb >> 2) & 1u);
                osrow[1023] = (float)stb;
                otrow[0]    = (float)(thb & 1u);
                otrow[1]    = (float)((thb >> 1) & 1u);
                otrow[2]    = (float)((thb >> 2) & 1u);
                otrow[1023] = (float)ttb;
            }
        }
    }

    // wave reduction (per-wave sums <= 8192 each, fits 16-bit packed)
    unsigned int comb = (mism << 16) | live;
    #pragma unroll
    for (int m = 1; m < 64; m <<= 1)
        comb += (unsigned int)__shfl_xor((int)comb, m, 64);
    if (lane == 0) wsum[wave] = comb;
    __syncthreads();

    // block reduction -> ONE u64 atomic per block (no fences here).
    if (tid == 0) {
        unsigned int bm = 0, bl = 0;
        #pragma unroll
        for (int i = 0; i < NWAVES; ++i) {
            bm += wsum[i] >> 16;
            bl += wsum[i] & 0xFFFFu;
        }
        atomicAdd(counters, ((u64)bm << 32) | (u64)bl);
    }
}

__global__ void gol_finalize(const u64* __restrict__ counters,
                             float* __restrict__ out)
{
    u64 c = *counters;
    unsigned int mism = (unsigned int)(c >> 32);
    unsigned int live = (unsigned int)(c & 0xFFFFFFFFULL);
    out[0]            = (float)((double)mism / (double)NTOT);
    out[1 + 2*NTOT]   = (float)live;
    out[2 + 2*NTOT]   = (mism > 0) ? 1.0f : 0.0f;
}

extern "C" void kernel_launch(void* const* d_in, const int* in_sizes, int n_in,
                              void* d_out, int out_size, void* d_ws, size_t ws_size,
                              hipStream_t stream) {
    (void)in_sizes; (void)n_in; (void)out_size; (void)ws_size;
    const float* in_state = (const float*)d_in[0];
    const float* target   = (const float*)d_in[1];
    float* out = (float*)d_out;
    u64* counters = (u64*)d_ws;

    hipMemsetAsync(d_ws, 0, sizeof(u64), stream);

    gol_fused<<<dim3(GRID), dim3(THREADS), 0, stream>>>(in_state, target, out, counters);
    gol_finalize<<<1, 1, 0, stream>>>(counters, out);
}

// Round 5
// 459.483 us; speedup vs baseline: 1.0174x; 1.0174x over previous
//
#include <hip/hip_runtime.h>
#include <cstdint>

typedef unsigned long long u64;

#define BATCH   32
#define H       1024
#define W       1024
#define WPR     16                 // 64-bit words per row (1024/64)
#define TR      64                 // interior rows per tile
#define HALO    8                  // = generations
#define BR      (TR + 2*HALO)      // 80 buffer rows
#define BRP     (BR + 2)           // +2 zero-pad rows -> 82
#define WP      (WPR + 2)          // +2 zero-pad word-cols -> 18
#define THREADS 512
#define NWAVES  (THREADS/64)       // 8
#define GENS    8
#define GRID    (BATCH * (H / TR)) // 512 blocks
#define NTOT    33554432ULL        // B*H*W

__device__ __forceinline__ u64 shflxor64(u64 v, int m) {
    return (u64)__shfl_xor((long long)v, m, 64);
}

// Horizontal 3-cell adder for one row: o = low bit, t = carry bit of (W+C+E).
__device__ __forceinline__ void hrow(u64 L, u64 C, u64 R, u64& o, u64& t) {
    u64 wv = (C << 1) | (L >> 63);
    u64 ev = (C >> 1) | (R << 63);
    o = wv ^ C ^ ev;
    t = (wv & C) | (ev & (wv ^ C));
}

// Combine 3 row-sums (2-bit each) -> next-state word. mid = center row word.
__device__ __forceinline__ u64 life_next(u64 oA, u64 tA, u64 oB, u64 tB,
                                         u64 oC, u64 tC, u64 mid) {
    u64 oa = oA ^ oB ^ oC;
    u64 oc = (oA & oB) | (oC & (oA ^ oB));
    u64 ts = tA ^ tB ^ tC;
    u64 tc = (tA & tB) | (tC & (tA ^ tB));
    u64 b1 = oc ^ ts;
    u64 cc = oc & ts;
    u64 b2 = cc ^ tc;
    u64 b3 = cc & tc;
    u64 eq3 = oa & b1 & ~(b2 | b3);          // sum9 == 3
    u64 eq4 = (~oa) & (~b1) & b2 & (~b3);    // sum9 == 4
    return eq3 | (mid & eq4);
}

// Round-3 structure (proven 461.0 us) + ONE change: the 134 MB target-copy
// write stream is moved INTO the gens steps (tbits is complete in LDS before
// gens; each of 8 waves reconstructs+stores one target row per step = 64 rows
// over 8 steps), so those stores stream while HBM is otherwise idle during
// gens VALU. Epilogue = state write + mism/live reduction only.
__global__ __launch_bounds__(THREADS)
void gol_fused(const float* __restrict__ in_state,
               const float* __restrict__ target,
               float* __restrict__ out,
               u64* __restrict__ counters)
{
    __shared__ u64 buf[2][BRP][WP];      // 2*82*18*8 = 23616 B
    __shared__ u64 tbits[TR][WPR + 1];   // 64*17*8   =  8704 B (+1 zero col)
    __shared__ unsigned int wsum[NWAVES];

    const int tile = blockIdx.x;             // 0..511
    const int tpb  = H / TR;                 // 16 tiles per batch
    const int b    = tile / tpb;
    const int r0   = (tile - b * tpb) * TR;  // first interior global row

    const int tid  = threadIdx.x;
    const int wave = tid >> 6;
    const int lane = tid & 63;

    // Zero both gen-buffers (pads + out-of-range rows must stay zero).
    for (int i = tid; i < 2 * BRP * WP; i += THREADS)
        ((u64*)buf)[i] = 0ULL;
    if (tid < TR) tbits[tid][WPR] = 0ULL;    // zero pad word for shifted reads
    __syncthreads();

    const size_t boff = (size_t)b * H * W;
    const float* inb  = in_state + boff;

    const int sub   = lane & 15;
    const int wsub  = lane >> 4;

    // ---- pack in_state: buffer row br (0..BR-1) <- global row r0-HALO+br ----
    for (int br = wave; br < BR; br += NWAVES) {
        int gr = r0 - HALO + br;
        if (gr < 0 || gr >= H) continue;    // wave-uniform
        const float4* rowp4 = (const float4*)(inb + (size_t)gr * W);
        #pragma unroll
        for (int g = 0; g < 4; ++g) {
            float4 f = rowp4[g * 64 + lane];
            u64 nib = (u64)((f.x > 0.5f) | ((f.y > 0.5f) << 1) |
                            ((f.z > 0.5f) << 2) | ((f.w > 0.5f) << 3));
            u64 v = nib << (sub * 4);
            v |= shflxor64(v, 1);
            v |= shflxor64(v, 2);
            v |= shflxor64(v, 4);
            v |= shflxor64(v, 8);
            if (sub == 0)
                buf[0][br + 1][g * 4 + wsub + 1] = v;
        }
    }

    // ---- pack target rows (all interior, always in range) ----
    for (int lr = wave; lr < TR; lr += NWAVES) {
        const float4* rowp4 = (const float4*)(target + boff + (size_t)(r0 + lr) * W);
        #pragma unroll
        for (int g = 0; g < 4; ++g) {
            float4 f = rowp4[g * 64 + lane];
            u64 nib = (u64)((f.x > 0.5f) | ((f.y > 0.5f) << 1) |
                            ((f.z > 0.5f) << 2) | ((f.w > 0.5f) << 3));
            u64 v = nib << (sub * 4);
            v |= shflxor64(v, 1);
            v |= shflxor64(v, 2);
            v |= shflxor64(v, 4);
            v |= shflxor64(v, 8);
            if (sub == 0)
                tbits[lr][g * 4 + wsub] = v;
        }
    }
    __syncthreads();

    // out layout: out[0]=loss, out[1..]=state, out[1+NTOT..]=target copy.
    float* o_state = out + 1;
    float* o_tgt   = out + 1 + NTOT;

    // ---- 8 generations; each step ALSO streams 8 target rows to global ----
    // State s valid on buffer rows [s, 79-s]; step s computes state s+1 on
    // [s+1, 78-s] (width 78-2s even -> clean row pairs).
    int cur = 0;
    for (int step = 0; step < GENS; ++step) {
        // target-copy slice: wave writes row lr (reconstructed from tbits).
        // Stores are fire-and-forget; they drain during this step's VALU.
        {
            const int lr = step * NWAVES + wave;     // 0..63
            size_t rowbase = boff + (size_t)(r0 + lr) * W;
            const u64* trow = &tbits[lr][0];         // [0..15] data, [16]=0 pad
            float* otrow = o_tgt + rowbase;
            #pragma unroll
            for (int g = 0; g < 4; ++g) {
                int k = g * 64 + lane;
                if (k < 255) {
                    int bitbase = 4 * k + 3;
                    int w0 = bitbase >> 6;
                    int sh = bitbase & 63;           // never 0
                    u64 tlo = trow[w0], thi = trow[w0 + 1];
                    unsigned tb = (unsigned)(((tlo >> sh) | (thi << (64 - sh))) & 0xFULL);
                    float4 tv;
                    tv.x = (float)(tb & 1u);
                    tv.y = (float)((tb >> 1) & 1u);
                    tv.z = (float)((tb >> 2) & 1u);
                    tv.w = (float)((tb >> 3) & 1u);
                    *(float4*)(otrow + bitbase) = tv;   // aligned
                } else {
                    u64 tfirst = trow[0], tlast = trow[15];
                    unsigned thb = (unsigned)(tfirst & 7ULL);
                    unsigned ttb = (unsigned)(tlast >> 63);
                    otrow[0]    = (float)(thb & 1u);
                    otrow[1]    = (float)((thb >> 1) & 1u);
                    otrow[2]    = (float)((thb >> 2) & 1u);
                    otrow[1023] = (float)ttb;
                }
            }
        }

        const int lo     = step + 1;            // first output buffer-row
        const int npairs = 39 - step;           // (78-2*step)/2
        const int items  = npairs * WPR;
        for (int idx = tid; idx < items; idx += THREADS) {
            int pr  = idx >> 4;
            int c   = (idx & 15) + 1;
            int br0 = lo + 2 * pr;              // first output row of pair
            int r   = br0 + 1;                  // array row (pad offset)

            u64 o0, t0, o1, t1, o2, t2, o3, t3, mB, mC;
            { u64 L = buf[cur][r-1][c-1], C = buf[cur][r-1][c], R = buf[cur][r-1][c+1];
              hrow(L, C, R, o0, t0); }
            { u64 L = buf[cur][r  ][c-1], C = buf[cur][r  ][c], R = buf[cur][r  ][c+1];
              hrow(L, C, R, o1, t1); mB = C; }
            { u64 L = buf[cur][r+1][c-1], C = buf[cur][r+1][c], R = buf[cur][r+1][c+1];
              hrow(L, C, R, o2, t2); mC = C; }
            { u64 L = buf[cur][r+2][c-1], C = buf[cur][r+2][c], R = buf[cur][r+2][c+1];
              hrow(L, C, R, o3, t3); }

            u64 n0 = life_next(o0, t0, o1, t1, o2, t2, mB);
            u64 n1 = life_next(o1, t1, o2, t2, o3, t3, mC);

            int gr0 = r0 - HALO + br0;
            buf[cur ^ 1][r    ][c] = (gr0     >= 0 && gr0     < H) ? n0 : 0ULL;
            buf[cur ^ 1][r + 1][c] = (gr0 + 1 >= 0 && gr0 + 1 < H) ? n1 : 0ULL;
        }
        __syncthreads();
        cur ^= 1;
    }
    // After 8 flips cur == 0; state-8 valid on rows [HALO, HALO+TR-1].

    // ---- epilogue: state write + reduction (target already written).
    // Shifted quads: quad k covers row elements 4k+3..4k+6; out index
    // rowbase + 1 + 4k+3 === 0 mod 4 -> all float4 stores aligned.
    unsigned int mism = 0, live = 0;
    for (int lr = wave; lr < TR; lr += NWAVES) {
        int br = HALO + lr;
        int gr = r0 + lr;
        size_t rowbase = boff + (size_t)gr * W;
        const u64* wrow = &buf[cur][br + 1][1];   // wrow[0..15] data, wrow[16]=0 pad
        const u64* trow = &tbits[lr][0];          // trow[0..15] data, trow[16]=0 pad
        float* osrow = o_state + rowbase;
        #pragma unroll
        for (int g = 0; g < 4; ++g) {
            int k = g * 64 + lane;
            if (k < 255) {
                int bitbase = 4 * k + 3;
                int w0 = bitbase >> 6;
                int sh = bitbase & 63;            // in {3,7,...,63}, never 0
                u64 slo = wrow[w0], shi = wrow[w0 + 1];
                u64 tlo = trow[w0], thi = trow[w0 + 1];
                unsigned sb = (unsigned)(((slo >> sh) | (shi << (64 - sh))) & 0xFULL);
                unsigned tb = (unsigned)(((tlo >> sh) | (thi << (64 - sh))) & 0xFULL);
                mism += (unsigned)__popc(sb ^ tb);
                live += (unsigned)__popc(sb);
                float4 sv;
                sv.x = (float)(sb & 1u);
                sv.y = (float)((sb >> 1) & 1u);
                sv.z = (float)((sb >> 2) & 1u);
                sv.w = (float)((sb >> 3) & 1u);
                *(float4*)(osrow + bitbase) = sv;   // aligned
            } else {
                // head elements 0,1,2 and tail element 1023
                u64 sfirst = wrow[0],  slast = wrow[15];
                u64 tfirst = trow[0],  tlast = trow[15];
                unsigned shb = (unsigned)(sfirst & 7ULL);
                unsigned thb = (unsigned)(tfirst & 7ULL);
                unsigned stb = (unsigned)(slast >> 63);
                unsigned ttb = (unsigned)(tlast >> 63);
                mism += (unsigned)__popc(shb ^ thb) + (stb ^ ttb);
                live += (unsigned)__popc(shb) + stb;
                osrow[0]    = (float)(shb & 1u);
                osrow[1]    = (float)((shb >> 1) & 1u);
                osrow[2]    = (float)((shb >> 2) & 1u);
                osrow[1023] = (float)stb;
            }
        }
    }

    // wave reduction (per-wave sums <= 8192 each, fits 16-bit packed)
    unsigned int comb = (mism << 16) | live;
    #pragma unroll
    for (int m = 1; m < 64; m <<= 1)
        comb += (unsigned int)__shfl_xor((int)comb, m, 64);
    if (lane == 0) wsum[wave] = comb;
    __syncthreads();

    // block reduction -> ONE u64 atomic per block (no fences here).
    if (tid == 0) {
        unsigned int bm = 0, bl = 0;
        #pragma unroll
        for (int i = 0; i < NWAVES; ++i) {
            bm += wsum[i] >> 16;
            bl += wsum[i] & 0xFFFFu;
        }
        atomicAdd(counters, ((u64)bm << 32) | (u64)bl);
    }
}

__global__ void gol_finalize(const u64* __restrict__ counters,
                             float* __restrict__ out)
{
    u64 c = *counters;
    unsigned int mism = (unsigned int)(c >> 32);
    unsigned int live = (unsigned int)(c & 0xFFFFFFFFULL);
    out[0]            = (float)((double)mism / (double)NTOT);
    out[1 + 2*NTOT]   = (float)live;
    out[2 + 2*NTOT]   = (mism > 0) ? 1.0f : 0.0f;
}

extern "C" void kernel_launch(void* const* d_in, const int* in_sizes, int n_in,
                              void* d_out, int out_size, void* d_ws, size_t ws_size,
                              hipStream_t stream) {
    (void)in_sizes; (void)n_in; (void)out_size; (void)ws_size;
    const float* in_state = (const float*)d_in[0];
    const float* target   = (const float*)d_in[1];
    float* out = (float*)d_out;
    u64* counters = (u64*)d_ws;

    hipMemsetAsync(d_ws, 0, sizeof(u64), stream);

    gol_fused<<<dim3(GRID), dim3(THREADS), 0, stream>>>(in_state, target, out, counters);
    gol_finalize<<<1, 1, 0, stream>>>(counters, out);
}